// Round 10
// baseline (168.847 us; speedup 1.0000x reference)
//
#include <hip/hip_runtime.h>
#include <stdint.h>
#include <stddef.h>

// Problem constants
#define HOUT 64
#define WOUT 64
#define CIN  32
#define COUT 16
#define SLOC 4096          // HOUT*WOUT
#define KTOT 288           // CIN*9
#define HPAD 66            // 64 + 2 pad
#define WPAD 148           // dwords per n-row of LDS W tile (9*16=144 + 4 pad)
// Padded-X pixel block = BATCH*CIN bf16 = 2048 ushorts = 4096 bytes

typedef __attribute__((ext_vector_type(8))) short  short8;   // 8 bf16 (4 VGPRs)
typedef __attribute__((ext_vector_type(4))) float  floatx4;  // MFMA acc / float4
typedef __attribute__((ext_vector_type(2))) float  floatx2;

// fp32 -> bf16 round-to-nearest-even (bit pattern)
static __device__ __forceinline__ unsigned short f2bf(float f) {
    union { float f; unsigned int u; } v; v.f = f;
    unsigned int u = v.u;
    unsigned int r = (u + 0x7FFFu + ((u >> 16) & 1u)) >> 16;
    return (unsigned short)r;
}

// ---------------------------------------------------------------------------
// Prep kernel: border-zero + X transpose + Wg L3-prefetch. 2048 x 256.
// R10 single-variable change vs R6: stream ALL of Wg (75.5 MB, 9 dwordx4
// per thread) through L3. Loads are issued FIRST (latency hides under the
// latency-bound transpose, prep runs at only 2.2 TB/s with idle issue
// slots); values kept alive with asm volatile (rule #17: prevents DCE
// without cost). Each iteration's 302 MB workspace-poison fill evicts L3,
// so without this varconv's W chain starts from cold HBM (~900 cy).
// ---------------------------------------------------------------------------
__global__ __launch_bounds__(256) void prep_kernel(const float* __restrict__ X,
                                                   const float* __restrict__ Wg,
                                                   unsigned short* __restrict__ xt) {
    const int id  = blockIdx.x;
    const int tid = threadIdx.x;

    // ---- Wg L3-prefetch: 4,718,592 uint4 = 9 per thread, issued first ----
    const uint4* wsrc = (const uint4*)Wg;
    const unsigned gid = id * 256 + tid;          // 0..524287
    uint4 pf[9];
#pragma unroll
    for (int g = 0; g < 9; ++g)
        pf[g] = wsrc[(size_t)g * 524288u + gid];

    // ---- border zero: 260 x 4KB pixel blocks, handled by blocks 0..259 ----
    if (id < 260) {
        int h1, w1;
        if (id < 66)       { h1 = 0;  w1 = id; }
        else if (id < 132) { h1 = 65; w1 = id - 66; }
        else { int r = id - 132; h1 = (r >> 1) + 1; w1 = (r & 1) ? 65 : 0; }
        ((uint4*)(xt + (size_t)(h1 * HPAD + w1) * 2048))[tid] = uint4{0u, 0u, 0u, 0u};
    }

    // ---- transpose X[b][c][h][w] fp32 -> xt[(h+1)][(w+1)][b][c] bf16 ----
    const int w   = tid >> 2;        // 0..63
    const int cg8 = (tid & 3) * 8;   // channel group base
#pragma unroll
    for (int u = 0; u < 2; ++u) {
        const int unit = id * 2 + u;            // 0..4095
        const int h = unit >> 6, b = unit & 63;
        const float* xb = X + (((size_t)b * CIN + cg8) * HOUT + h) * WOUT + w;
        unsigned short v[8];
#pragma unroll
        for (int j = 0; j < 8; ++j)
            v[j] = f2bf(xb[(size_t)j * HOUT * WOUT]);
        uint4 pack;
        pack.x = (unsigned)v[0] | ((unsigned)v[1] << 16);
        pack.y = (unsigned)v[2] | ((unsigned)v[3] << 16);
        pack.z = (unsigned)v[4] | ((unsigned)v[5] << 16);
        pack.w = (unsigned)v[6] | ((unsigned)v[7] << 16);
        *(uint4*)(xt + (size_t)((h + 1) * HPAD + (w + 1)) * 2048 + b * CIN + cg8) = pack;
    }

    // ---- consume prefetch values (no-op asm keeps loads live, forces L3 fill) ----
#pragma unroll
    for (int g = 0; g < 9; ++g)
        asm volatile("" :: "v"(pf[g].x), "v"(pf[g].y), "v"(pf[g].z), "v"(pf[g].w));
}

// ---------------------------------------------------------------------------
// Main kernel (R6 verbatim -- measured best, 155.4): block = 2 sites x 64
// batches, 256 thr, grid 2048, one barrier, batched-ILP loads,
// conflict-free LDS W layout.
//   phase 1: issue ALL 10 staging dwordx4 into fA[5]/fB[5]   (40 VGPR)
//   phase 2: issue ALL A-fragments; sites share 2/3 tap-cols -> 12 unique
//            loads (af[3][4], 48 VGPR) cover both sites' 18 MFMAs
//   phase 3: one vmcnt drain -> f2bf + LDS scatter + colsum shfl
//   phase 4: barrier -> ds_read_b128 B-frags + MFMA on resident A-regs
// ---------------------------------------------------------------------------
__global__ __launch_bounds__(256, 4) void varconv_kernel(const unsigned short* __restrict__ xt,
                                                         const float* __restrict__ Wg,
                                                         const float* __restrict__ bias,
                                                         float* __restrict__ out) {
    __shared__ __align__(16) unsigned int wru[2][16 * WPAD];  // 2 sites, 18.5 KB
    __shared__ float cs[2][4][16];                            // colsum partials

    const int id   = blockIdx.x;                   // 0..2047
    const int sg   = (id & 7) * 256 + (id >> 3);   // site-group, XCD-contiguous
    const int s0   = sg * 2;
    const int y    = s0 >> 6;
    const int x0   = s0 & 63;                      // even; x0+3 <= 65 within pad
    const int tid  = threadIdx.x;
    const int lane = tid & 63;
    const int wv   = tid >> 6;                     // batch quarter
    const int q    = lane >> 4;                    // channel octet
    const int n    = lane & 15;                    // c_out (B/D); batch-in-quarter (A)
    const int B0   = wv * 16;

    // ---- phase 1: issue all staging loads (both sites, 36 KB contiguous) ----
    const uint4* wsrc = (const uint4*)(Wg + (size_t)s0 * (KTOT * COUT));
    uint4 fA[5], fB[5];
#pragma unroll
    for (int it = 0; it < 5; ++it) {
        const int tau  = tid + it * 256;           // 0..1279; 1152 real tasks
        const int tt   = tau < 1152 ? tau : 1151;  // dup-load tail (masked later)
        const int site = tt >= 576;
        const int t2   = tt - 576 * site;
        const int ng = t2 & 3, cp = (t2 >> 2) & 15, t = t2 >> 6;
        const int kA = 18 * cp + t;                // row c=2cp ; +9 -> c=2cp+1
        fA[it] = wsrc[site * 1152 + kA * 4 + ng];
        fB[it] = wsrc[site * 1152 + (kA + 9) * 4 + ng];
    }

    // ---- phase 2: issue all A-fragment loads (12 shared across both sites) ----
    const unsigned short* abase = xt + (size_t)(B0 + n) * CIN + q * 8;
    short8 af[3][4];
#pragma unroll
    for (int cy = 0; cy < 3; ++cy)
#pragma unroll
        for (int cx = 0; cx < 4; ++cx)
            af[cy][cx] = *(const short8*)(abase + (size_t)((y + cy) * HPAD + (x0 + cx)) * 2048);

    // ---- phase 3: convert + conflict-free LDS scatter + colsum ----
    // LDS dword L(n,t,cp) = n*WPAD + t*16 + cp packs bf16(W[2cp*9+t][n]) |
    // bf16(W[(2cp+1)*9+t][n])<<16. Per wave-instr t is constant -> 16 cp's x
    // ng-parity = 2 lanes/bank (free). Explicit site branches keep cacc in
    // registers (no runtime-indexed register arrays -> no scratch).
    float cacc0[4] = {0.f, 0.f, 0.f, 0.f};
    float cacc1[4] = {0.f, 0.f, 0.f, 0.f};
#pragma unroll
    for (int it = 0; it < 5; ++it) {
        const int tau = tid + it * 256;
        if (tau < 1152) {
            union { uint4 u; float f[4]; } a, b;
            a.u = fA[it]; b.u = fB[it];
            if (tau < 576) {
                const int ng = tau & 3, cp = (tau >> 2) & 15, t = tau >> 6;
#pragma unroll
                for (int m = 0; m < 4; ++m) {
                    cacc0[m] += a.f[m] + b.f[m];
                    wru[0][(4 * ng + m) * WPAD + t * 16 + cp] =
                        (unsigned)f2bf(a.f[m]) | ((unsigned)f2bf(b.f[m]) << 16);
                }
            } else {
                const int t2 = tau - 576;
                const int ng = t2 & 3, cp = (t2 >> 2) & 15, t = t2 >> 6;
#pragma unroll
                for (int m = 0; m < 4; ++m) {
                    cacc1[m] += a.f[m] + b.f[m];
                    wru[1][(4 * ng + m) * WPAD + t * 16 + cp] =
                        (unsigned)f2bf(a.f[m]) | ((unsigned)f2bf(b.f[m]) << 16);
                }
            }
        }
    }

    // reduce colsums over lanes sharing ng (= tid&3) within the wave
#pragma unroll
    for (int m = 0; m < 4; ++m) {
        cacc0[m] += __shfl_xor(cacc0[m], 4, 64);
        cacc1[m] += __shfl_xor(cacc1[m], 4, 64);
        cacc0[m] += __shfl_xor(cacc0[m], 8, 64);
        cacc1[m] += __shfl_xor(cacc1[m], 8, 64);
        cacc0[m] += __shfl_xor(cacc0[m], 16, 64);
        cacc1[m] += __shfl_xor(cacc1[m], 16, 64);
        cacc0[m] += __shfl_xor(cacc0[m], 32, 64);
        cacc1[m] += __shfl_xor(cacc1[m], 32, 64);
    }
    if (lane < 4) {                                // lane == ng; holds n = 4*lane+m
#pragma unroll
        for (int m = 0; m < 4; ++m) {
            cs[0][wv][4 * lane + m] = cacc0[m];
            cs[1][wv][4 * lane + m] = cacc1[m];
        }
    }

    __syncthreads();

    // ---- phase 4: B-frags from LDS + 18 MFMAs on resident A-regs ----
    // Read ds_read_b128 at n*WPAD + t*16 + 4q: 8 dwords/bank (b128 minimum).
    floatx4 acc0 = {0.f, 0.f, 0.f, 0.f};
    floatx4 acc1 = {0.f, 0.f, 0.f, 0.f};
    const unsigned int* w0 = &wru[0][n * WPAD + 4 * q];
    const unsigned int* w1 = &wru[1][n * WPAD + 4 * q];
#pragma unroll
    for (int t = 0; t < 9; ++t) {
        const int cy = t / 3, cx = t % 3;
        const short8 b0 = *(const short8*)(w0 + t * 16);
        acc0 = __builtin_amdgcn_mfma_f32_16x16x32_bf16(af[cy][cx], b0, acc0, 0, 0, 0);
        const short8 b1 = *(const short8*)(w1 + t * 16);
        acc1 = __builtin_amdgcn_mfma_f32_16x16x32_bf16(af[cy][cx + 1], b1, acc1, 0, 0, 0);
    }
    const float badd0 = bias[s0] *     (cs[0][0][n] + cs[0][1][n] + cs[0][2][n] + cs[0][3][n]);
    const float badd1 = bias[s0 + 1] * (cs[1][0][n] + cs[1][1][n] + cs[1][2][n] + cs[1][3][n]);

    // ---- epilogue: lane (q,n) holds rows b=B0+4q+r, col c=n, 2 consec s ----
#pragma unroll
    for (int r = 0; r < 4; ++r) {
        const int b = B0 + 4 * q + r;
        float* dst = out + ((size_t)(b * COUT + n)) * SLOC + s0;
        *(floatx2*)dst = floatx2{acc0[r] + badd0, acc1[r] + badd1};
    }
}

extern "C" void kernel_launch(void* const* d_in, const int* in_sizes, int n_in,
                              void* d_out, int out_size, void* d_ws, size_t ws_size,
                              hipStream_t stream) {
    const float* X    = (const float*)d_in[0];   // [64][32][64][64] fp32
    const float* Wg   = (const float*)d_in[1];   // [4096][288][16] fp32
    const float* bias = (const float*)d_in[2];   // [4096] fp32
    float* out = (float*)d_out;                  // [64][16][4096] fp32

    // Workspace: xt only: 66*66*64*32*2 = 17,842,176 B
    unsigned short* xt = (unsigned short*)d_ws;

    prep_kernel<<<2048, 256, 0, stream>>>(X, Wg, xt);
    varconv_kernel<<<2048, 256, 0, stream>>>(xt, Wg, bias, out);
}

// Round 11
// 166.526 us; speedup vs baseline: 1.0139x; 1.0139x over previous
//
#include <hip/hip_runtime.h>
#include <stdint.h>
#include <stddef.h>

// Problem constants
#define HOUT 64
#define WOUT 64
#define CIN  32
#define COUT 16
#define SLOC 4096          // HOUT*WOUT
#define KTOT 288           // CIN*9
#define HPAD 66            // 64 + 2 pad
#define WPAD 148           // dwords per n-row of LDS W tile (9*16=144 + 4 pad)
// Padded-X pixel block = BATCH*CIN bf16 = 2048 ushorts = 4096 bytes

typedef __attribute__((ext_vector_type(8))) short  short8;   // 8 bf16 (4 VGPRs)
typedef __attribute__((ext_vector_type(4))) float  floatx4;  // MFMA acc / float4
typedef __attribute__((ext_vector_type(2))) float  floatx2;

// fp32 -> bf16 round-to-nearest-even (bit pattern)
static __device__ __forceinline__ unsigned short f2bf(float f) {
    union { float f; unsigned int u; } v; v.f = f;
    unsigned int u = v.u;
    unsigned int r = (u + 0x7FFFu + ((u >> 16) & 1u)) >> 16;
    return (unsigned short)r;
}

// ---------------------------------------------------------------------------
// Prep kernel: Wg L3-prefetch + border-zero + X transpose. 2048 x 256.
// R10 post-mortem: asm-consume-at-end let the scheduler SINK the 9 pf loads
// to the kernel tail (VGPR=36 = exactly the pf batch), serializing
// transpose-then-prefetch per wave: 13+36 = 49us at 1.5 TB/s. R11 pins the
// loads at the top with sched_barrier(0): 25 VMEM in flight, one drain,
// BW-bound. (varconv with L3-warm Wg measured ~17us in R10 -- the win.)
// ---------------------------------------------------------------------------
__global__ __launch_bounds__(256) void prep_kernel(const float* __restrict__ X,
                                                   const float* __restrict__ Wg,
                                                   unsigned short* __restrict__ xt) {
    const int id  = blockIdx.x;
    const int tid = threadIdx.x;

    // ---- P1: issue Wg prefetch loads (9 x dwordx4, lane-coalesced 1KB/instr) ----
    const uint4* wsrc = (const uint4*)Wg;
    const unsigned gid = id * 256 + tid;          // 0..524287; 9*524288 = all of Wg
    uint4 pf0 = wsrc[gid];
    uint4 pf1 = wsrc[gid +     524288u];
    uint4 pf2 = wsrc[gid + 2u * 524288u];
    uint4 pf3 = wsrc[gid + 3u * 524288u];
    uint4 pf4 = wsrc[gid + 4u * 524288u];
    uint4 pf5 = wsrc[gid + 5u * 524288u];
    uint4 pf6 = wsrc[gid + 6u * 524288u];
    uint4 pf7 = wsrc[gid + 7u * 524288u];
    uint4 pf8 = wsrc[gid + 8u * 524288u];

    // ---- P2: issue X transpose loads (2 units x 8 channels) ----
    const int w   = tid >> 2;        // 0..63
    const int cg8 = (tid & 3) * 8;   // channel group base
    const int unit0 = id * 2;
    const int h0 = unit0 >> 6, b0 = unit0 & 63;
    const int h1b = (unit0 + 1) >> 6, b1b = (unit0 + 1) & 63;
    const float* xb0 = X + (((size_t)b0 * CIN + cg8) * HOUT + h0) * WOUT + w;
    const float* xb1 = X + (((size_t)b1b * CIN + cg8) * HOUT + h1b) * WOUT + w;
    float xv0[8], xv1[8];
#pragma unroll
    for (int j = 0; j < 8; ++j) xv0[j] = xb0[(size_t)j * HOUT * WOUT];
#pragma unroll
    for (int j = 0; j < 8; ++j) xv1[j] = xb1[(size_t)j * HOUT * WOUT];

    // ---- pin: no instruction may cross -> pf loads cannot sink below ----
    __builtin_amdgcn_sched_barrier(0);

    // ---- border zero: 260 x 4KB pixel blocks, handled by blocks 0..259 ----
    if (id < 260) {
        int h1, w1;
        if (id < 66)       { h1 = 0;  w1 = id; }
        else if (id < 132) { h1 = 65; w1 = id - 66; }
        else { int r = id - 132; h1 = (r >> 1) + 1; w1 = (r & 1) ? 65 : 0; }
        ((uint4*)(xt + (size_t)(h1 * HPAD + w1) * 2048))[tid] = uint4{0u, 0u, 0u, 0u};
    }

    // ---- transpose pack + store (waits X; X is newer than pf -> pf drains too) ----
    {
        unsigned short v[8];
#pragma unroll
        for (int j = 0; j < 8; ++j) v[j] = f2bf(xv0[j]);
        uint4 pack;
        pack.x = (unsigned)v[0] | ((unsigned)v[1] << 16);
        pack.y = (unsigned)v[2] | ((unsigned)v[3] << 16);
        pack.z = (unsigned)v[4] | ((unsigned)v[5] << 16);
        pack.w = (unsigned)v[6] | ((unsigned)v[7] << 16);
        *(uint4*)(xt + (size_t)((h0 + 1) * HPAD + (w + 1)) * 2048 + b0 * CIN + cg8) = pack;
#pragma unroll
        for (int j = 0; j < 8; ++j) v[j] = f2bf(xv1[j]);
        pack.x = (unsigned)v[0] | ((unsigned)v[1] << 16);
        pack.y = (unsigned)v[2] | ((unsigned)v[3] << 16);
        pack.z = (unsigned)v[4] | ((unsigned)v[5] << 16);
        pack.w = (unsigned)v[6] | ((unsigned)v[7] << 16);
        *(uint4*)(xt + (size_t)((h1b + 1) * HPAD + (w + 1)) * 2048 + b1b * CIN + cg8) = pack;
    }

    // ---- consume pf (vmcnt already drained by the X waits -> free) ----
    asm volatile("" :: "v"(pf0.x), "v"(pf0.y), "v"(pf0.z), "v"(pf0.w));
    asm volatile("" :: "v"(pf1.x), "v"(pf1.y), "v"(pf1.z), "v"(pf1.w));
    asm volatile("" :: "v"(pf2.x), "v"(pf2.y), "v"(pf2.z), "v"(pf2.w));
    asm volatile("" :: "v"(pf3.x), "v"(pf3.y), "v"(pf3.z), "v"(pf3.w));
    asm volatile("" :: "v"(pf4.x), "v"(pf4.y), "v"(pf4.z), "v"(pf4.w));
    asm volatile("" :: "v"(pf5.x), "v"(pf5.y), "v"(pf5.z), "v"(pf5.w));
    asm volatile("" :: "v"(pf6.x), "v"(pf6.y), "v"(pf6.z), "v"(pf6.w));
    asm volatile("" :: "v"(pf7.x), "v"(pf7.y), "v"(pf7.z), "v"(pf7.w));
    asm volatile("" :: "v"(pf8.x), "v"(pf8.y), "v"(pf8.z), "v"(pf8.w));
}

// ---------------------------------------------------------------------------
// Main kernel (R6 verbatim -- measured ~17us with L3-warm Wg in R10):
// block = 2 sites x 64 batches, 256 thr, grid 2048, one barrier,
// batched-ILP loads, conflict-free LDS W layout.
// ---------------------------------------------------------------------------
__global__ __launch_bounds__(256, 4) void varconv_kernel(const unsigned short* __restrict__ xt,
                                                         const float* __restrict__ Wg,
                                                         const float* __restrict__ bias,
                                                         float* __restrict__ out) {
    __shared__ __align__(16) unsigned int wru[2][16 * WPAD];  // 2 sites, 18.5 KB
    __shared__ float cs[2][4][16];                            // colsum partials

    const int id   = blockIdx.x;                   // 0..2047
    const int sg   = (id & 7) * 256 + (id >> 3);   // site-group, XCD-contiguous
    const int s0   = sg * 2;
    const int y    = s0 >> 6;
    const int x0   = s0 & 63;                      // even; x0+3 <= 65 within pad
    const int tid  = threadIdx.x;
    const int lane = tid & 63;
    const int wv   = tid >> 6;                     // batch quarter
    const int q    = lane >> 4;                    // channel octet
    const int n    = lane & 15;                    // c_out (B/D); batch-in-quarter (A)
    const int B0   = wv * 16;

    // ---- phase 1: issue all staging loads (both sites, 36 KB contiguous) ----
    const uint4* wsrc = (const uint4*)(Wg + (size_t)s0 * (KTOT * COUT));
    uint4 fA[5], fB[5];
#pragma unroll
    for (int it = 0; it < 5; ++it) {
        const int tau  = tid + it * 256;           // 0..1279; 1152 real tasks
        const int tt   = tau < 1152 ? tau : 1151;  // dup-load tail (masked later)
        const int site = tt >= 576;
        const int t2   = tt - 576 * site;
        const int ng = t2 & 3, cp = (t2 >> 2) & 15, t = t2 >> 6;
        const int kA = 18 * cp + t;                // row c=2cp ; +9 -> c=2cp+1
        fA[it] = wsrc[site * 1152 + kA * 4 + ng];
        fB[it] = wsrc[site * 1152 + (kA + 9) * 4 + ng];
    }

    // ---- phase 2: issue all A-fragment loads (12 shared across both sites) ----
    const unsigned short* abase = xt + (size_t)(B0 + n) * CIN + q * 8;
    short8 af[3][4];
#pragma unroll
    for (int cy = 0; cy < 3; ++cy)
#pragma unroll
        for (int cx = 0; cx < 4; ++cx)
            af[cy][cx] = *(const short8*)(abase + (size_t)((y + cy) * HPAD + (x0 + cx)) * 2048);

    // ---- phase 3: convert + conflict-free LDS scatter + colsum ----
    float cacc0[4] = {0.f, 0.f, 0.f, 0.f};
    float cacc1[4] = {0.f, 0.f, 0.f, 0.f};
#pragma unroll
    for (int it = 0; it < 5; ++it) {
        const int tau = tid + it * 256;
        if (tau < 1152) {
            union { uint4 u; float f[4]; } a, b;
            a.u = fA[it]; b.u = fB[it];
            if (tau < 576) {
                const int ng = tau & 3, cp = (tau >> 2) & 15, t = tau >> 6;
#pragma unroll
                for (int m = 0; m < 4; ++m) {
                    cacc0[m] += a.f[m] + b.f[m];
                    wru[0][(4 * ng + m) * WPAD + t * 16 + cp] =
                        (unsigned)f2bf(a.f[m]) | ((unsigned)f2bf(b.f[m]) << 16);
                }
            } else {
                const int t2 = tau - 576;
                const int ng = t2 & 3, cp = (t2 >> 2) & 15, t = t2 >> 6;
#pragma unroll
                for (int m = 0; m < 4; ++m) {
                    cacc1[m] += a.f[m] + b.f[m];
                    wru[1][(4 * ng + m) * WPAD + t * 16 + cp] =
                        (unsigned)f2bf(a.f[m]) | ((unsigned)f2bf(b.f[m]) << 16);
                }
            }
        }
    }

    // reduce colsums over lanes sharing ng (= tid&3) within the wave
#pragma unroll
    for (int m = 0; m < 4; ++m) {
        cacc0[m] += __shfl_xor(cacc0[m], 4, 64);
        cacc1[m] += __shfl_xor(cacc1[m], 4, 64);
        cacc0[m] += __shfl_xor(cacc0[m], 8, 64);
        cacc1[m] += __shfl_xor(cacc1[m], 8, 64);
        cacc0[m] += __shfl_xor(cacc0[m], 16, 64);
        cacc1[m] += __shfl_xor(cacc1[m], 16, 64);
        cacc0[m] += __shfl_xor(cacc0[m], 32, 64);
        cacc1[m] += __shfl_xor(cacc1[m], 32, 64);
    }
    if (lane < 4) {                                // lane == ng; holds n = 4*lane+m
#pragma unroll
        for (int m = 0; m < 4; ++m) {
            cs[0][wv][4 * lane + m] = cacc0[m];
            cs[1][wv][4 * lane + m] = cacc1[m];
        }
    }

    __syncthreads();

    // ---- phase 4: B-frags from LDS + 18 MFMAs on resident A-regs ----
    floatx4 acc0 = {0.f, 0.f, 0.f, 0.f};
    floatx4 acc1 = {0.f, 0.f, 0.f, 0.f};
    const unsigned int* w0 = &wru[0][n * WPAD + 4 * q];
    const unsigned int* w1 = &wru[1][n * WPAD + 4 * q];
#pragma unroll
    for (int t = 0; t < 9; ++t) {
        const int cy = t / 3, cx = t % 3;
        const short8 b0 = *(const short8*)(w0 + t * 16);
        acc0 = __builtin_amdgcn_mfma_f32_16x16x32_bf16(af[cy][cx], b0, acc0, 0, 0, 0);
        const short8 b1 = *(const short8*)(w1 + t * 16);
        acc1 = __builtin_amdgcn_mfma_f32_16x16x32_bf16(af[cy][cx + 1], b1, acc1, 0, 0, 0);
    }
    const float badd0 = bias[s0] *     (cs[0][0][n] + cs[0][1][n] + cs[0][2][n] + cs[0][3][n]);
    const float badd1 = bias[s0 + 1] * (cs[1][0][n] + cs[1][1][n] + cs[1][2][n] + cs[1][3][n]);

    // ---- epilogue: lane (q,n) holds rows b=B0+4q+r, col c=n, 2 consec s ----
#pragma unroll
    for (int r = 0; r < 4; ++r) {
        const int b = B0 + 4 * q + r;
        float* dst = out + ((size_t)(b * COUT + n)) * SLOC + s0;
        *(floatx2*)dst = floatx2{acc0[r] + badd0, acc1[r] + badd1};
    }
}

extern "C" void kernel_launch(void* const* d_in, const int* in_sizes, int n_in,
                              void* d_out, int out_size, void* d_ws, size_t ws_size,
                              hipStream_t stream) {
    const float* X    = (const float*)d_in[0];   // [64][32][64][64] fp32
    const float* Wg   = (const float*)d_in[1];   // [4096][288][16] fp32
    const float* bias = (const float*)d_in[2];   // [4096] fp32
    float* out = (float*)d_out;                  // [64][16][4096] fp32

    // Workspace: xt only: 66*66*64*32*2 = 17,842,176 B
    unsigned short* xt = (unsigned short*)d_ws;

    prep_kernel<<<2048, 256, 0, stream>>>(X, Wg, xt);
    varconv_kernel<<<2048, 256, 0, stream>>>(xt, Wg, bias, out);
}